// Round 1
// baseline (161.145 us; speedup 1.0000x reference)
//
#include <hip/hip_runtime.h>
#include <math.h>

// Problem constants (from reference setup_inputs)
#define BB   32    // batch
#define CC   256   // channels
#define HF   64    // feature H
#define WF   64    // feature W
#define NN   256   // grid points (16x16, step 4)
#define ROWS 16    // n-rows per sim block
#define NTILES (NN / ROWS)  // 16

__device__ inline float waveSum(float v) {
#pragma unroll
    for (int off = 32; off > 0; off >>= 1) v += __shfl_xor(v, off, 64);
    return v;
}

// Kernel A: gather grid points, L2-normalize across channels, write
//   D[b][n][c]  (row-major, for uniform broadcast in GEMM)
//   R[b][c][m]  (c-major, coalesced in m for GEMM)
//   GV[b][n]    (grid_valid as 0/1 float)
__global__ void gather_norm_kernel(const float* __restrict__ fr,
                                   const float* __restrict__ fd,
                                   const float* __restrict__ vm,
                                   float* __restrict__ D,
                                   float* __restrict__ R,
                                   float* __restrict__ GV) {
    int blk = blockIdx.x;       // b*NN + n
    int b = blk >> 8;
    int n = blk & 255;
    int i = n >> 4, j = n & 15;
    int y = 4 * i, x = 4 * j;   // grid point in 64x64 fmap
    int c = threadIdx.x;

    size_t base = ((size_t)(b * CC + c) * HF + y) * WF + x;
    float vd = fd[base];
    float vr = fr[base];

    __shared__ float red[8];
    float sd = waveSum(vd * vd);
    float sr = waveSum(vr * vr);
    int wv = c >> 6, ln = c & 63;
    if (ln == 0) { red[wv] = sd; red[4 + wv] = sr; }
    __syncthreads();
    float ssd = red[0] + red[1] + red[2] + red[3];
    float ssr = red[4] + red[5] + red[6] + red[7];
    float nd = fmaxf(sqrtf(ssd), 1e-12f);
    float nr = fmaxf(sqrtf(ssr), 1e-12f);

    D[(size_t)blk * CC + c] = vd / nd;
    R[((size_t)b * CC + c) * NN + n] = vr / nr;

    if (c == 0) {
        // grid_valid: valid_mask[b, 0, 32*i, 32*j] > 0.5
        float v = vm[((size_t)b * 512 + 32 * i) * 512 + 32 * j];
        GV[blk] = (v > 0.5f) ? 1.0f : 0.0f;
    }
}

// Kernel B: per (b, 16-row tile): sim rows, masked logsumexp, argmax, diag,
// accumulate row_loss*vf and correct-count partials.
__global__ void sim_loss_kernel(const float* __restrict__ D,
                                const float* __restrict__ R,
                                const float* __restrict__ GV,
                                float* __restrict__ lossPart,
                                float* __restrict__ corrPart) {
    __shared__ float redv[4];
    __shared__ int   redi[4];
    __shared__ float redsum[4];
    __shared__ float diagLds[ROWS];

    int b = blockIdx.x >> 4;             // NTILES == 16 tiles per batch
    int tile = blockIdx.x & (NTILES - 1);
    int nbase = tile * ROWS;
    int m = threadIdx.x;                 // column index 0..255

    const float* Drow = D + ((size_t)b * NN + nbase) * CC;  // 16 rows x 256
    const float* Rb   = R + (size_t)b * CC * NN;

    float acc[ROWS];
#pragma unroll
    for (int k = 0; k < ROWS; ++k) acc[k] = 0.0f;

    // Register-tiled GEMM: acc[k] = sum_c D[nbase+k][c] * R[c][m]
    for (int c4 = 0; c4 < CC / 4; ++c4) {
        float4 dv[ROWS];
#pragma unroll
        for (int k = 0; k < ROWS; ++k)
            dv[k] = *reinterpret_cast<const float4*>(Drow + (size_t)k * CC + c4 * 4);
        float r0 = Rb[(size_t)(c4 * 4 + 0) * NN + m];
        float r1 = Rb[(size_t)(c4 * 4 + 1) * NN + m];
        float r2 = Rb[(size_t)(c4 * 4 + 2) * NN + m];
        float r3 = Rb[(size_t)(c4 * 4 + 3) * NN + m];
#pragma unroll
        for (int k = 0; k < ROWS; ++k) {
            acc[k] = fmaf(dv[k].x, r0, acc[k]);
            acc[k] = fmaf(dv[k].y, r1, acc[k]);
            acc[k] = fmaf(dv[k].z, r2, acc[k]);
            acc[k] = fmaf(dv[k].w, r3, acc[k]);
        }
    }

    const float invT = 1.0f / 0.07f;
    float gvm = GV[(size_t)b * NN + m];
    bool validm = (gvm > 0.5f);

    // diag: sim[nbase+k][nbase+k] lives in thread m == nbase+k, reg acc[k]
    int kd = m - nbase;
    if (kd >= 0 && kd < ROWS) diagLds[kd] = acc[kd] * invT;
    __syncthreads();

    float lossAcc = 0.0f, corrAcc = 0.0f;
    int wv = m >> 6, ln = m & 63;

    for (int k = 0; k < ROWS; ++k) {
        float simv = acc[k] * invT;
        float val = validm ? simv : -1e30f;

        // block-wide max + argmax (first-occurrence tie-break: min index)
        float v = val; int idx = m;
#pragma unroll
        for (int off = 32; off > 0; off >>= 1) {
            float ov = __shfl_xor(v, off, 64);
            int oi = __shfl_xor(idx, off, 64);
            if (ov > v || (ov == v && oi < idx)) { v = ov; idx = oi; }
        }
        if (ln == 0) { redv[wv] = v; redi[wv] = idx; }
        __syncthreads();
        float mx = redv[0]; int amx = redi[0];
#pragma unroll
        for (int w2 = 1; w2 < 4; ++w2) {
            float ov = redv[w2]; int oi = redi[w2];
            if (ov > mx || (ov == mx && oi < amx)) { mx = ov; amx = oi; }
        }
        __syncthreads();

        // sum exp(val - mx)
        float e = expf(val - mx);
        float s = waveSum(e);
        if (ln == 0) redsum[wv] = s;
        __syncthreads();

        if (m == 0) {
            float ssum = redsum[0] + redsum[1] + redsum[2] + redsum[3];
            float logZ = mx + logf(ssum);
            float vfn = GV[(size_t)b * NN + nbase + k];
            if (vfn > 0.5f) {
                lossAcc += (logZ - diagLds[k]);
                if (amx == nbase + k) corrAcc += 1.0f;
            }
        }
        __syncthreads();
    }

    if (m == 0) {
        lossPart[blockIdx.x] = lossAcc;
        corrPart[blockIdx.x] = corrAcc;
    }
}

// Kernel C: per-batch include / n_valid logic, final two scalars.
__global__ void finalize_kernel(const float* __restrict__ GV,
                                const float* __restrict__ lossPart,
                                const float* __restrict__ corrPart,
                                float* __restrict__ out) {
    __shared__ float sl[BB], sc[BB], st[BB];
    int t = threadIdx.x;
    if (t < BB) {
        float nv = 0.0f;
        for (int m = 0; m < NN; ++m) nv += GV[(size_t)t * NN + m];
        float lb = 0.0f, cb = 0.0f;
        for (int k = 0; k < NTILES; ++k) {
            lb += lossPart[t * NTILES + k];
            cb += corrPart[t * NTILES + k];
        }
        bool inc = (nv >= 2.0f);
        sl[t] = inc ? (lb / fmaxf(nv, 1.0f)) : 0.0f;
        sc[t] = inc ? cb : 0.0f;
        st[t] = inc ? nv : 0.0f;
    }
    __syncthreads();
    if (t == 0) {
        float L = 0.0f, Ccnt = 0.0f, Tcnt = 0.0f;
        for (int bb = 0; bb < BB; ++bb) { L += sl[bb]; Ccnt += sc[bb]; Tcnt += st[bb]; }
        float avg = L / (float)BB;
        out[0] = (Tcnt > 0.0f) ? avg : 0.0f;
        out[1] = (Tcnt > 0.0f) ? (Ccnt / fmaxf(Tcnt, 1.0f) * 100.0f) : 0.0f;
    }
}

extern "C" void kernel_launch(void* const* d_in, const int* in_sizes, int n_in,
                              void* d_out, int out_size, void* d_ws, size_t ws_size,
                              hipStream_t stream) {
    const float* fr = (const float*)d_in[0];  // fmap_rgb
    const float* fd = (const float*)d_in[1];  // fmap_depth
    // d_in[2] = projected_coords: DEAD in reference (_rgb_pos is never used)
    const float* vm = (const float*)d_in[3];  // valid_mask

    float* out = (float*)d_out;
    char* ws = (char*)d_ws;

    // Workspace layout (~16.8 MB total)
    float* D        = (float*)ws;                                      // BB*NN*CC
    float* R        = (float*)(ws + (size_t)BB * NN * CC * 4);         // BB*CC*NN
    float* GV       = (float*)(ws + (size_t)2 * BB * NN * CC * 4);     // BB*NN
    float* lossPart = GV + BB * NN;                                    // BB*NTILES
    float* corrPart = lossPart + BB * NTILES;                          // BB*NTILES

    hipLaunchKernelGGL(gather_norm_kernel, dim3(BB * NN), dim3(CC), 0, stream,
                       fr, fd, vm, D, R, GV);
    hipLaunchKernelGGL(sim_loss_kernel, dim3(BB * NTILES), dim3(NN), 0, stream,
                       D, R, GV, lossPart, corrPart);
    hipLaunchKernelGGL(finalize_kernel, dim3(1), dim3(64), 0, stream,
                       GV, lossPart, corrPart, out);
}

// Round 2
// 57.616 us; speedup vs baseline: 2.7969x; 2.7969x over previous
//
#include <hip/hip_runtime.h>
#include <math.h>

// Problem constants (from reference setup_inputs)
#define BB   32    // batch
#define CC   256   // channels
#define HF   64    // feature H
#define WF   64    // feature W
#define NN   256   // grid points (16x16, step 4)
#define ROWS 16    // n-rows per sim block
#define NTILES (NN / ROWS)  // 16

// ---------------------------------------------------------------------------
// Kernel A: coalesced gather + transpose (NO normalization here).
// Block = (b, cg) where cg indexes a 16-channel group. 256 threads.
// Reads the 16 needed rows (y=0,4,...,60) of each 64x64 map contiguously,
// transposes via padded LDS, writes:
//   Draw[b][n][c]  (n-major, raw depth features at grid points)
//   Rraw[b][c][m]  (c-major, raw rgb features at grid points)
//   GV[b][n]       (grid_valid 0/1)  -- only cg==0 blocks
// ---------------------------------------------------------------------------
__global__ __launch_bounds__(256) void gather_transpose_kernel(
        const float* __restrict__ fr,
        const float* __restrict__ fd,
        const float* __restrict__ vm,
        float* __restrict__ Draw,
        float* __restrict__ Rraw,
        float* __restrict__ GV) {
    __shared__ float ldsD[16][257];   // +1 pad: conflict-free column reads
    __shared__ float ldsR[16][257];

    int b  = blockIdx.x >> 4;
    int cg = blockIdx.x & 15;
    int t  = threadIdx.x;
    int i  = t >> 4, j = t & 15;          // grid point (i,j) -> (y,x)=(4i,4j)

    size_t mapBase = ((size_t)(b * CC + cg * 16)) * (HF * WF);
    size_t ptOff   = (size_t)(4 * i) * WF + 4 * j;

#pragma unroll
    for (int cc = 0; cc < 16; ++cc) {
        size_t a = mapBase + (size_t)cc * (HF * WF) + ptOff;
        ldsD[cc][t] = fd[a];   // lanes within a 16-group read one row: coalesced
        ldsR[cc][t] = fr[a];
    }
    __syncthreads();

    // Draw: thread t == n writes its 16-channel chunk (64B, line-aligned)
    float* dDst = Draw + ((size_t)(b * NN + t)) * CC + cg * 16;
#pragma unroll
    for (int q = 0; q < 4; ++q) {
        float4 o;
        o.x = ldsD[4 * q + 0][t];
        o.y = ldsD[4 * q + 1][t];
        o.z = ldsD[4 * q + 2][t];
        o.w = ldsD[4 * q + 3][t];
        *reinterpret_cast<float4*>(dDst + 4 * q) = o;
    }

    // Rraw: per channel, 256 contiguous floats (coalesced)
#pragma unroll
    for (int cc = 0; cc < 16; ++cc) {
        Rraw[((size_t)(b * CC + cg * 16 + cc)) * NN + t] = ldsR[cc][t];
    }

    if (cg == 0) {
        // grid_valid: valid_mask[b, 0, 32*i, 32*j] > 0.5 (coords downsampled x8, grid x4)
        float v = vm[((size_t)b * 512 + 32 * i) * 512 + 32 * j];
        GV[(size_t)b * NN + t] = (v > 0.5f) ? 1.0f : 0.0f;
    }
}

// ---------------------------------------------------------------------------
// Kernel B: per (b, 16-row tile): raw GEMM + on-the-fly normalization,
// masked logsumexp / argmax / diag, per-tile loss & correct partials.
// Block = 256 threads (thread = column m). D tile staged in LDS.
// ---------------------------------------------------------------------------
__global__ __launch_bounds__(256) void sim_loss_kernel(
        const float* __restrict__ Draw,
        const float* __restrict__ Rraw,
        const float* __restrict__ GV,
        float* __restrict__ lossPart,
        float* __restrict__ corrPart) {
    __shared__ float ldsD[ROWS * 256];   // D tile; reused for sim values later
    __shared__ float rowNorm[ROWS];
    __shared__ float diagLds[ROWS];
    __shared__ float rowLoss[ROWS];
    __shared__ float rowCorr[ROWS];

    int b     = blockIdx.x >> 4;
    int tile  = blockIdx.x & (NTILES - 1);
    int nbase = tile * ROWS;
    int t     = threadIdx.x;
    int m     = t;

    // ---- stage D tile (16 rows x 256 c, contiguous) + row sumsq ----
    const float* Dsrc = Draw + ((size_t)(b * NN + nbase)) * CC;
    float ss = 0.0f;
#pragma unroll
    for (int q = 0; q < 4; ++q) {
        float4 v = *reinterpret_cast<const float4*>(Dsrc + (size_t)t * 16 + 4 * q);
        *reinterpret_cast<float4*>(&ldsD[t * 16 + 4 * q]) = v;
        ss += v.x * v.x + v.y * v.y + v.z * v.z + v.w * v.w;
    }
    // reduce across the 16 threads owning row r = t>>4 (lanes stay in group)
#pragma unroll
    for (int off = 1; off < 16; off <<= 1) ss += __shfl_xor(ss, off, 64);
    if ((t & 15) == 0) rowNorm[t >> 4] = fmaxf(sqrtf(ss), 1e-12f);
    __syncthreads();

    // ---- register-tiled GEMM: acc[k] = sum_c D[k][c] * R[c][m]; also ||r_m||^2
    float acc[ROWS];
#pragma unroll
    for (int k = 0; k < ROWS; ++k) acc[k] = 0.0f;
    float rsq = 0.0f;

    const float* Rb = Rraw + (size_t)b * CC * NN + m;
    for (int c4 = 0; c4 < CC / 4; ++c4) {
        float r0 = Rb[(size_t)(4 * c4 + 0) * NN];
        float r1 = Rb[(size_t)(4 * c4 + 1) * NN];
        float r2 = Rb[(size_t)(4 * c4 + 2) * NN];
        float r3 = Rb[(size_t)(4 * c4 + 3) * NN];
        rsq = fmaf(r0, r0, rsq);
        rsq = fmaf(r1, r1, rsq);
        rsq = fmaf(r2, r2, rsq);
        rsq = fmaf(r3, r3, rsq);
#pragma unroll
        for (int k = 0; k < ROWS; ++k) {
            float4 d = *reinterpret_cast<const float4*>(&ldsD[k * 256 + c4 * 4]);
            acc[k] = fmaf(d.x, r0, acc[k]);
            acc[k] = fmaf(d.y, r1, acc[k]);
            acc[k] = fmaf(d.z, r2, acc[k]);
            acc[k] = fmaf(d.w, r3, acc[k]);
        }
    }

    const float invT = 1.0f / 0.07f;
    float nr = fmaxf(sqrtf(rsq), 1e-12f);
    float gvm = GV[(size_t)b * NN + m];
    bool validm = (gvm > 0.5f);

    __syncthreads();   // all GEMM reads of ldsD done before overwrite

    // ---- write scaled (+masked) sim rows into LDS; capture diag unmasked ----
#pragma unroll
    for (int k = 0; k < ROWS; ++k) {
        float s = acc[k] * invT / (rowNorm[k] * nr);
        if (m == nbase + k) diagLds[k] = s;
        ldsD[k * 256 + m] = validm ? s : -1e30f;
    }
    __syncthreads();

    // ---- one wave per row: max/argmax + sum-exp via shfl only ----
    int wv = t >> 6, ln = t & 63;
    for (int k = wv; k < ROWS; k += 4) {
        float v0 = ldsD[k * 256 + ln];
        float v1 = ldsD[k * 256 + 64 + ln];
        float v2 = ldsD[k * 256 + 128 + ln];
        float v3 = ldsD[k * 256 + 192 + ln];
        float mv = v0; int mi = ln;
        if (v1 > mv) { mv = v1; mi = ln + 64; }
        if (v2 > mv) { mv = v2; mi = ln + 128; }
        if (v3 > mv) { mv = v3; mi = ln + 192; }
#pragma unroll
        for (int off = 32; off > 0; off >>= 1) {
            float ov = __shfl_xor(mv, off, 64);
            int   oi = __shfl_xor(mi, off, 64);
            if (ov > mv || (ov == mv && oi < mi)) { mv = ov; mi = oi; }
        }
        float e = expf(v0 - mv) + expf(v1 - mv) + expf(v2 - mv) + expf(v3 - mv);
#pragma unroll
        for (int off = 32; off > 0; off >>= 1) e += __shfl_xor(e, off, 64);
        if (ln == 0) {
            float vfn = GV[(size_t)b * NN + nbase + k];
            float lz = mv + logf(e);
            rowLoss[k] = (vfn > 0.5f) ? (lz - diagLds[k]) : 0.0f;
            rowCorr[k] = (vfn > 0.5f && mi == nbase + k) ? 1.0f : 0.0f;
        }
    }
    __syncthreads();

    if (t == 0) {
        float la = 0.0f, ca = 0.0f;
#pragma unroll
        for (int k = 0; k < ROWS; ++k) { la += rowLoss[k]; ca += rowCorr[k]; }
        lossPart[blockIdx.x] = la;
        corrPart[blockIdx.x] = ca;
    }
}

// ---------------------------------------------------------------------------
// Kernel C: per-batch include / n_valid logic, final two scalars.
// ---------------------------------------------------------------------------
__global__ __launch_bounds__(256) void finalize_kernel(
        const float* __restrict__ GV,
        const float* __restrict__ lossPart,
        const float* __restrict__ corrPart,
        float* __restrict__ out) {
    __shared__ float sl[BB], sc2[BB], st2[BB];
    int t = threadIdx.x;           // 256 threads: 8 per batch
    int b = t >> 3, s = t & 7;

    float nvp = 0.0f;
    const float4* g4 = reinterpret_cast<const float4*>(GV + (size_t)b * NN);
#pragma unroll
    for (int q = 0; q < 8; ++q) {
        float4 v = g4[s * 8 + q];
        nvp += v.x + v.y + v.z + v.w;
    }
#pragma unroll
    for (int off = 1; off < 8; off <<= 1) nvp += __shfl_xor(nvp, off, 64);

    if (s == 0) {
        float lb = 0.0f, cb = 0.0f;
#pragma unroll
        for (int k = 0; k < NTILES; ++k) {
            lb += lossPart[b * NTILES + k];
            cb += corrPart[b * NTILES + k];
        }
        bool inc = (nvp >= 2.0f);
        sl[b]  = inc ? (lb / fmaxf(nvp, 1.0f)) : 0.0f;
        sc2[b] = inc ? cb : 0.0f;
        st2[b] = inc ? nvp : 0.0f;
    }
    __syncthreads();
    if (t == 0) {
        float L = 0.0f, Ccnt = 0.0f, Tcnt = 0.0f;
        for (int bb = 0; bb < BB; ++bb) { L += sl[bb]; Ccnt += sc2[bb]; Tcnt += st2[bb]; }
        float avg = L / (float)BB;
        out[0] = (Tcnt > 0.0f) ? avg : 0.0f;
        out[1] = (Tcnt > 0.0f) ? (Ccnt / fmaxf(Tcnt, 1.0f) * 100.0f) : 0.0f;
    }
}

extern "C" void kernel_launch(void* const* d_in, const int* in_sizes, int n_in,
                              void* d_out, int out_size, void* d_ws, size_t ws_size,
                              hipStream_t stream) {
    const float* fr = (const float*)d_in[0];  // fmap_rgb
    const float* fd = (const float*)d_in[1];  // fmap_depth
    // d_in[2] = projected_coords: DEAD in reference (_rgb_pos never used)
    const float* vm = (const float*)d_in[3];  // valid_mask

    float* out = (float*)d_out;
    char* ws = (char*)d_ws;

    // Workspace layout (~16.8 MB total)
    float* Draw     = (float*)ws;                                      // BB*NN*CC
    float* Rraw     = (float*)(ws + (size_t)BB * NN * CC * 4);         // BB*CC*NN
    float* GV       = (float*)(ws + (size_t)2 * BB * NN * CC * 4);     // BB*NN
    float* lossPart = GV + BB * NN;                                    // BB*NTILES
    float* corrPart = lossPart + BB * NTILES;                          // BB*NTILES

    hipLaunchKernelGGL(gather_transpose_kernel, dim3(BB * 16), dim3(256), 0, stream,
                       fr, fd, vm, Draw, Rraw, GV);
    hipLaunchKernelGGL(sim_loss_kernel, dim3(BB * NTILES), dim3(256), 0, stream,
                       Draw, Rraw, GV, lossPart, corrPart);
    hipLaunchKernelGGL(finalize_kernel, dim3(1), dim3(256), 0, stream,
                       GV, lossPart, corrPart, out);
}